// Round 11
// baseline (3080.869 us; speedup 1.0000x reference)
//
#include <hip/hip_runtime.h>
#include <cstdint>
#include <cmath>

#define NN_ 2708
#define NF_ 4096
#define MD_ 2048
#define NH_ 1024
#define NC_ 64
#define FITER 20
#define KPAD 2720   // 2708 padded to multiple of 32

// scal layout (floats in ws): [0]=c [1]=eta [2]=thr(lam/c) [3]=lam [4]=ynormsq [5..24]=rsq[k]

typedef _Float16 half8_t __attribute__((ext_vector_type(8)));
typedef _Float16 half4_t __attribute__((ext_vector_type(4)));
typedef float floatx4_t __attribute__((ext_vector_type(4)));

__device__ __forceinline__ float softt(float v, float t) {
    float a = fabsf(v) - t;
    a = a > 0.f ? a : 0.f;
    return copysignf(a, v);
}

// supports blockDim 256 or 512 (nw <= 8)
__device__ __forceinline__ float blockReduceSum(float v, float* red) {
    int lane = threadIdx.x & 63, wid = threadIdx.x >> 6;
    #pragma unroll
    for (int off = 32; off; off >>= 1) v += __shfl_down(v, off);
    if (lane == 0) red[wid] = v;
    __syncthreads();
    if (wid == 0) {
        int nw = (blockDim.x + 63) >> 6;
        float r = (lane < nw) ? red[lane] : 0.f;
        #pragma unroll
        for (int off = 4; off; off >>= 1) r += __shfl_down(r, off);
        if (lane == 0) red[0] = r;
    }
    __syncthreads();
    float out = red[0];
    __syncthreads();
    return out;
}

// ---------- threefry2x32 + JAX normal init ----------
__device__ __forceinline__ float erfinv_f(float x) {
    float w = -log1pf(-x * x);
    float p;
    if (w < 5.0f) {
        w -= 2.5f;
        p = 2.81022636e-08f;
        p = fmaf(p, w, 3.43273939e-07f);
        p = fmaf(p, w, -3.5233877e-06f);
        p = fmaf(p, w, -4.39150654e-06f);
        p = fmaf(p, w, 0.00021858087f);
        p = fmaf(p, w, -0.00125372503f);
        p = fmaf(p, w, -0.00417768164f);
        p = fmaf(p, w, 0.246640727f);
        p = fmaf(p, w, 1.50140941f);
    } else {
        w = sqrtf(w) - 3.0f;
        p = -0.000200214257f;
        p = fmaf(p, w, 0.000100950558f);
        p = fmaf(p, w, 0.00134934322f);
        p = fmaf(p, w, -0.00367342844f);
        p = fmaf(p, w, 0.00573950773f);
        p = fmaf(p, w, -0.0076224613f);
        p = fmaf(p, w, 0.00943887047f);
        p = fmaf(p, w, 1.00167406f);
        p = fmaf(p, w, 2.83297682f);
    }
    return p * x;
}

__device__ __forceinline__ float u32_to_normal(uint32_t bits) {
    uint32_t fb = (bits >> 9) | 0x3F800000u;
    float f = __uint_as_float(fb) - 1.0f;        // [0,1)
    const float lo = -0.99999994f;               // nextafter(-1,0) in f32
    float u = fmaf(f, 2.0f, lo);
    u = fmaxf(lo, u);
    return 1.41421356f * erfinv_f(u);
}

__global__ void init_x0_kernel(float* __restrict__ X0) {
    int i = blockIdx.x * blockDim.x + threadIdx.x;   // 0..1023 pairs
    if (i >= MD_ / 2) return;
    uint32_t x0 = (uint32_t)i, x1 = (uint32_t)(i + MD_ / 2);
    const uint32_t k0 = 0u, k1 = 1u, k2 = 0x1BD11BDBu;
    const uint32_t ks[3] = {k0, k1, k2};
    x0 += k0; x1 += k1;
    const int rot[8] = {13, 15, 26, 6, 17, 29, 16, 24};
    #pragma unroll
    for (int g = 0; g < 5; ++g) {
        const int base = (g & 1) ? 4 : 0;
        #pragma unroll
        for (int rr = 0; rr < 4; ++rr) {
            x0 += x1;
            int r = rot[base + rr];
            x1 = (x1 << r) | (x1 >> (32 - r));
            x1 ^= x0;
        }
        x0 += ks[(g + 1) % 3];
        x1 += ks[(g + 2) % 3] + (uint32_t)(g + 1);
    }
    X0[i] = u32_to_normal(x0);
    X0[i + MD_ / 2] = u32_to_normal(x1);
}

__global__ void zero_scal_kernel(float* __restrict__ scal) {
    int t = threadIdx.x;
    if (t < 32) scal[t] = 0.f;
}

__global__ void fill0_kernel(uint32_t* __restrict__ p, int n32) {
    int i = blockIdx.x * blockDim.x + threadIdx.x;
    if (i < n32) p[i] = 0u;
}

__global__ void sumsq_kernel(const float* __restrict__ X, int n, float* __restrict__ acc) {
    __shared__ float red[8];
    float s = 0.f;
    for (size_t i = (size_t)blockIdx.x * blockDim.x + threadIdx.x; i < (size_t)n;
         i += (size_t)gridDim.x * blockDim.x) {
        float v = X[i];
        s += v * v;
    }
    s = blockReduceSum(s, red);
    if (threadIdx.x == 0) atomicAdd(acc, s);
}

// ---------- transpose + split fp32 -> f16 hi/lo, out[c][r] padded to Rpad ----------
__global__ void tsplit_kernel(const float* __restrict__ src, int R, int ld, int Rpad,
                              _Float16* __restrict__ hi, _Float16* __restrict__ lo) {
    __shared__ float t[32][33];
    int rb = blockIdx.y * 32, cb = blockIdx.x * 32;
    int tx = threadIdx.x & 31, ty = threadIdx.x >> 5;   // ty 0..7
    #pragma unroll
    for (int s = 0; s < 32; s += 8) {
        int r = rb + ty + s, c = cb + tx;
        t[ty + s][tx] = (r < R) ? src[(size_t)r * ld + c] : 0.f;
    }
    __syncthreads();
    #pragma unroll
    for (int s = 0; s < 32; s += 8) {
        int c = cb + ty + s, r = rb + tx;
        float v = t[tx][ty + s];
        _Float16 h = (_Float16)v;
        size_t o = (size_t)c * Rpad + r;
        hi[o] = h;
        lo[o] = (_Float16)(v - (float)h);
    }
}

// ---------- fp32 -> f16 hi-only, non-transposed, zero row-padding ----------
// grid.x = Rpad, rows >= R write zeros; C multiple of 4
__global__ void splitrows_hi_kernel(const float* __restrict__ src, int R, int C,
                                    _Float16* __restrict__ hi) {
    int r = blockIdx.x;
    _Float16* d = hi + (size_t)r * C;
    if (r < R) {
        const float* s = src + (size_t)r * C;
        for (int c = threadIdx.x * 4; c < C; c += 1024) {
            float4 v = *reinterpret_cast<const float4*>(s + c);
            half4_t h;
            h[0] = (_Float16)v.x; h[1] = (_Float16)v.y;
            h[2] = (_Float16)v.z; h[3] = (_Float16)v.w;
            *reinterpret_cast<half4_t*>(d + c) = h;
        }
    } else {
        for (int c = threadIdx.x * 4; c < C; c += 1024) {
            half4_t h = {(_Float16)0.f, (_Float16)0.f, (_Float16)0.f, (_Float16)0.f};
            *reinterpret_cast<half4_t*>(d + c) = h;
        }
    }
}

// ---------- adj -> f16 hi-only, [2816][2720] zero-padded (2708 % 4 == 0) ----------
__global__ void splitadj_hi_kernel(const float* __restrict__ adj, _Float16* __restrict__ hi) {
    int r = blockIdx.x;   // 0..2815
    bool rok = r < NN_;
    _Float16* d = hi + (size_t)r * KPAD;
    const float* s = adj + (size_t)r * NN_;
    for (int c = threadIdx.x * 4; c < KPAD; c += 1024) {
        half4_t h = {(_Float16)0.f, (_Float16)0.f, (_Float16)0.f, (_Float16)0.f};
        if (rok && c + 3 < NN_) {
            float4 v = *reinterpret_cast<const float4*>(s + c);
            h[0] = (_Float16)v.x; h[1] = (_Float16)v.y;
            h[2] = (_Float16)v.z; h[3] = (_Float16)v.w;
        }
        *reinterpret_cast<half4_t*>(d + c) = h;
    }
}

// ---------- Gamma0 = soft(eta*BmT, lam) elementwise over [NF][MD] ----------
// All buffers share the row-major [n][m] layout -> fully coalesced, no LDS transpose.
// Values bit-identical to the old transposing version (same inputs per element).
__global__ void g0_kernel(const float* __restrict__ BmT, const float* __restrict__ scal,
                          float* __restrict__ GammaT,
                          _Float16* __restrict__ Zh, _Float16* __restrict__ Zl) {
    float eta = scal[1], lam = scal[3];
    size_t i = ((size_t)blockIdx.x * blockDim.x + threadIdx.x) * 4;
    float4 b = *reinterpret_cast<const float4*>(BmT + i);
    float4 g;
    g.x = softt(eta * b.x, lam);
    g.y = softt(eta * b.y, lam);
    g.z = softt(eta * b.z, lam);
    g.w = softt(eta * b.w, lam);
    *reinterpret_cast<float4*>(GammaT + i) = g;
    half4_t hh, ll;
    hh[0] = (_Float16)g.x; ll[0] = (_Float16)(g.x - (float)hh[0]);
    hh[1] = (_Float16)g.y; ll[1] = (_Float16)(g.y - (float)hh[1]);
    hh[2] = (_Float16)g.z; ll[2] = (_Float16)(g.z - (float)hh[2]);
    hh[3] = (_Float16)g.w; ll[3] = (_Float16)(g.w - (float)hh[3]);
    *reinterpret_cast<half4_t*>(Zh + i) = hh;
    *reinterpret_cast<half4_t*>(Zl + i) = ll;
}

// ---------- power step, NON-cooperative: one plain launch per apply ----------
__global__ __launch_bounds__(256)
void papply_kernel(const _Float16* __restrict__ Mh, const _Float16* __restrict__ Ml,
                   const float* __restrict__ Xc, float* __restrict__ Xn, int addI) {
    __shared__ float xs[MD_];
    __shared__ float red[8];
    const int tid = threadIdx.x;
    float ss = 0.f;
    for (int k = tid; k < MD_; k += 256) { float v = Xc[k]; xs[k] = v; ss += v * v; }
    __syncthreads();
    ss = blockReduceSum(ss, red);
    float inv = 1.0f / sqrtf(ss);
    const int w = tid >> 6, l = tid & 63;
    const int r = blockIdx.x * 4 + w;
    const _Float16* mhr = Mh + (size_t)r * MD_;
    const _Float16* mlr = Ml + (size_t)r * MD_;
    float s = 0.f;
    #pragma unroll
    for (int q = 0; q < 8; ++q) {
        int o = (q * 64 + l) * 4;
        half4_t hv = *reinterpret_cast<const half4_t*>(mhr + o);
        half4_t lv = *reinterpret_cast<const half4_t*>(mlr + o);
        float4 xv = *reinterpret_cast<const float4*>(&xs[o]);
        s = fmaf((float)hv[0] + (float)lv[0], xv.x, s);
        s = fmaf((float)hv[1] + (float)lv[1], xv.y, s);
        s = fmaf((float)hv[2] + (float)lv[2], xv.z, s);
        s = fmaf((float)hv[3] + (float)lv[3], xv.w, s);
    }
    #pragma unroll
    for (int off = 32; off; off >>= 1) s += __shfl_down(s, off);
    if (l == 0) Xn[r] = (s + (addI ? xs[r] : 0.f)) * inv;
}

// ---------- finalize: c = ||Xf||, eta, thr ----------
__global__ void pfinal_kernel(const float* __restrict__ Xf, const int* __restrict__ Kp,
                              float* __restrict__ scal) {
    __shared__ float red[8];
    float ss = 0.f;
    for (int k = threadIdx.x; k < MD_; k += 256) { float v = Xf[k]; ss += v * v; }
    ss = blockReduceSum(ss, red);
    if (threadIdx.x == 0) {
        float c = sqrtf(ss);
        float lam = (float)Kp[0];
        scal[0] = c;
        scal[1] = 1.0f / c;
        scal[2] = lam / c;
        scal[3] = lam;
    }
}

// ---------- split-f16 MFMA GEMM, 128x128 tile, BK=32, 512 threads (8 waves) ----------
// Modes (products per K-step, per element, in order — bit-compatible selections):
//   MO_BHL  : Ah·Bh + Ah·Bl          (wave grid 2x4; stage Ah,Bh,Bl)
//   MO_AHL  : Ah·Bh + Al·Bh          (wave grid 4x2; stage Ah,Al,Bh)  — used for
//             operand-SWAPPED GEMMs: same scalar products as BHL with roles exchanged.
//   MO_THREE: Ah·Bh + Ah·Bl + Al·Bh  (stage all 4)
//   MO_AFP32: fp32 A split in-kernel (sync path)
// LDS tiles XOR-swizzled (bank-conflict-free, verified 8.4M->0); f16 paths use the
// 3-buffer depth-2 pipeline with COUNTED vmcnt across raw s_barrier (T4).
// Workgroup mapping IDENTITY (round-5: XCD chunk swizzle destroyed B-column L2 reuse).
enum { ME_STORE = 0, ME_SYMSPLIT = 1, ME_SYMSPLIT_MI = 2, ME_H1 = 3, ME_SYMSPLIT16 = 4,
       ME_SPLIT_T = 5, ME_FISTAG = 6, ME_FISTAG_LAST = 7, ME_BIAS = 8, ME_BIASRELU = 9 };
enum { MO_BHL = 0, MO_AHL = 1, MO_THREE = 2, MO_AFP32 = 3 };

// 512 threads: each thread issues exactly one 16B global_load_lds chunk (128x32 f16 = 8KB)
__device__ __forceinline__ void stage_h(const _Float16* __restrict__ g, int row0, int K, int kk,
                                        _Float16* s, int tid) {
    const int row = tid >> 2;
    const int kg = (tid & 3) ^ ((row >> 1) & 3);        // inverse-swizzled source chunk
    const _Float16* gp = g + (size_t)(row0 + row) * K + kk + (kg << 3);
    _Float16* lp = s + ((size_t)((tid >> 6) * 64) << 3);   // wave-uniform base, lane*16B auto
    __builtin_amdgcn_global_load_lds(
        (const __attribute__((address_space(1))) void*)gp,
        (__attribute__((address_space(3))) void*)lp, 16, 0, 0);
}

template <int MODE>
__global__ __launch_bounds__(512)
void mgemm_kernel(const _Float16* __restrict__ Ah, const _Float16* __restrict__ Al,
                  const float* __restrict__ Afp, int Marr,
                  const _Float16* __restrict__ Bh, const _Float16* __restrict__ Bl,
                  int K, int Mvalid, int Nvalid, int ldc,
                  float* __restrict__ C, const float* __restrict__ BmP,
                  const float* __restrict__ bias,
                  _Float16* __restrict__ Th, _Float16* __restrict__ Tl, int Tstride,
                  const float* __restrict__ scal, float betak,
                  float* __restrict__ nrm_acc, int epi) {
    constexpr int TILE = 128 * 32;
    constexpr int TPB = (MODE == MO_THREE) ? 4 : 3;     // tiles per pipeline buffer
    constexpr int NT = (MODE == MO_AFP32) ? 4 : 3 * TPB;    // 32 / 72 / 96 KB
    constexpr bool A4 = (MODE == MO_AHL);               // 4x2 wave grid (keeps 8 LDS reads/wave)
    constexpr int WTR = A4 ? 32 : 64, WTC = A4 ? 64 : 32;
    constexpr int AI = WTR / 16, BJ = WTC / 16;
    constexpr int BOFF = (MODE == MO_BHL) ? 1 : 2;      // B-hi tile slot within a set
    __shared__ __align__(16) _Float16 smem[NT * TILE];
    float* red = (float*)smem;                          // epilogue-only alias (LDS dead then)
    const int tid = threadIdx.x;
    const int w = tid >> 6, l = tid & 63;
    const int wr = A4 ? (w >> 1) : (w >> 2);
    const int wc = A4 ? (w & 1) : (w & 3);
    const int quad = l >> 4, lc = l & 15;
    const int row0 = blockIdx.y * 128, col0 = blockIdx.x * 128;
    const int qs = (quad ^ ((lc >> 1) & 3)) << 3;       // swizzled chunk

    floatx4_t acc[AI][BJ];
    #pragma unroll
    for (int i = 0; i < AI; ++i)
        #pragma unroll
        for (int j = 0; j < BJ; ++j) {
            floatx4_t z = {0.f, 0.f, 0.f, 0.f};
            acc[i][j] = z;
        }

    if constexpr (MODE != MO_AFP32) {
        const int NTK = K >> 5;                         // K-tiles
        auto STAGE = [&](int kt, int b) {
            _Float16* base = smem + b * (TPB * TILE);
            stage_h(Ah, row0, K, kt << 5, base, tid);
            if constexpr (MODE == MO_AHL || MODE == MO_THREE)
                stage_h(Al, row0, K, kt << 5, base + TILE, tid);
            stage_h(Bh, col0, K, kt << 5, base + BOFF * TILE, tid);
            if constexpr (MODE == MO_BHL || MODE == MO_THREE)
                stage_h(Bl, col0, K, kt << 5, base + (BOFF + 1) * TILE, tid);
        };
        // prologue: stage tiles 0,1 into bufs 0,1; wait tile0 only (counted)
        STAGE(0, 0);
        if (NTK > 1) {
            STAGE(1, 1);
            if constexpr (TPB == 4) asm volatile("s_waitcnt vmcnt(4)" ::: "memory");
            else                    asm volatile("s_waitcnt vmcnt(3)" ::: "memory");
        } else {
            asm volatile("s_waitcnt vmcnt(0)" ::: "memory");
        }
        __builtin_amdgcn_s_barrier();
        for (int t = 0; t < NTK; ++t) {
            const int cur = t % 3;
            if (t + 2 < NTK) STAGE(t + 2, (t + 2) % 3);   // issue depth-2 prefetch (no wait)
            const _Float16* base = smem + cur * (TPB * TILE);
            const _Float16* pAh = base;
            const _Float16* pAl = base + TILE;
            const _Float16* pBh = base + BOFF * TILE;
            const _Float16* pBl = base + (BOFF + 1) * TILE;
            half8_t fAh[AI], fAl[AI], fBh[BJ], fBl[BJ];
            #pragma unroll
            for (int i = 0; i < AI; ++i) {
                int oa = (wr * WTR + i * 16 + lc) * 32 + qs;
                fAh[i] = *reinterpret_cast<const half8_t*>(&pAh[oa]);
                if constexpr (MODE == MO_AHL || MODE == MO_THREE)
                    fAl[i] = *reinterpret_cast<const half8_t*>(&pAl[oa]);
            }
            #pragma unroll
            for (int j = 0; j < BJ; ++j) {
                int ob = (wc * WTC + j * 16 + lc) * 32 + qs;
                fBh[j] = *reinterpret_cast<const half8_t*>(&pBh[ob]);
                if constexpr (MODE == MO_BHL || MODE == MO_THREE)
                    fBl[j] = *reinterpret_cast<const half8_t*>(&pBl[ob]);
            }
            #pragma unroll
            for (int i = 0; i < AI; ++i)
                #pragma unroll
                for (int j = 0; j < BJ; ++j) {
                    acc[i][j] = __builtin_amdgcn_mfma_f32_16x16x32_f16(fAh[i], fBh[j], acc[i][j], 0, 0, 0);
                    if constexpr (MODE == MO_BHL || MODE == MO_THREE)
                        acc[i][j] = __builtin_amdgcn_mfma_f32_16x16x32_f16(fAh[i], fBl[j], acc[i][j], 0, 0, 0);
                    if constexpr (MODE == MO_AHL || MODE == MO_THREE)
                        acc[i][j] = __builtin_amdgcn_mfma_f32_16x16x32_f16(fAl[i], fBh[j], acc[i][j], 0, 0, 0);
                }
            // pin ds_read+MFMA before the barrier, then COUNTED wait: tile t+1's loads
            // (issued at t-1) must have landed; tile t+2's TPB loads may stay in flight.
            __builtin_amdgcn_sched_barrier(0);
            if (t + 2 < NTK) {
                if constexpr (TPB == 4) asm volatile("s_waitcnt vmcnt(4)" ::: "memory");
                else                    asm volatile("s_waitcnt vmcnt(3)" ::: "memory");
            } else {
                asm volatile("s_waitcnt vmcnt(0)" ::: "memory");
            }
            __builtin_amdgcn_s_barrier();
        }
    } else {
        _Float16* sAh = smem;
        _Float16* sAl = smem + TILE;
        _Float16* sBh = smem + 2 * TILE;
        _Float16* sBl = smem + 3 * TILE;
        for (int kk = 0; kk < K; kk += 32) {
            #pragma unroll
            for (int p = 0; p < 2; ++p) {
                int c2 = p * 512 + tid;                 // 0..1023
                int r2 = c2 >> 3, k4 = (c2 & 7) << 2;
                int gr = row0 + r2;
                gr = gr < Marr ? gr : Marr - 1;         // clamp; masked at store
                float4 v = *reinterpret_cast<const float4*>(Afp + (size_t)gr * K + kk + k4);
                half4_t hh, ll;
                hh[0] = (_Float16)v.x; ll[0] = (_Float16)(v.x - (float)hh[0]);
                hh[1] = (_Float16)v.y; ll[1] = (_Float16)(v.y - (float)hh[1]);
                hh[2] = (_Float16)v.z; ll[2] = (_Float16)(v.z - (float)hh[2]);
                hh[3] = (_Float16)v.w; ll[3] = (_Float16)(v.w - (float)hh[3]);
                int sw = (((k4 >> 3) ^ ((r2 >> 1) & 3)) << 3) | (k4 & 7);   // swizzled write
                *reinterpret_cast<half4_t*>(&sAh[r2 * 32 + sw]) = hh;
                *reinterpret_cast<half4_t*>(&sAl[r2 * 32 + sw]) = ll;
            }
            stage_h(Bh, col0, K, kk, sBh, tid);
            stage_h(Bl, col0, K, kk, sBl, tid);
            asm volatile("s_waitcnt vmcnt(0)" ::: "memory");
            __syncthreads();

            half8_t fAh[AI], fAl[AI], fBh[BJ], fBl[BJ];
            #pragma unroll
            for (int i = 0; i < AI; ++i) {
                int oa = (wr * WTR + i * 16 + lc) * 32 + qs;
                fAh[i] = *reinterpret_cast<const half8_t*>(&sAh[oa]);
                fAl[i] = *reinterpret_cast<const half8_t*>(&sAl[oa]);
            }
            #pragma unroll
            for (int j = 0; j < BJ; ++j) {
                int ob = (wc * WTC + j * 16 + lc) * 32 + qs;
                fBh[j] = *reinterpret_cast<const half8_t*>(&sBh[ob]);
                fBl[j] = *reinterpret_cast<const half8_t*>(&sBl[ob]);
            }
            #pragma unroll
            for (int i = 0; i < AI; ++i)
                #pragma unroll
                for (int j = 0; j < BJ; ++j) {
                    acc[i][j] = __builtin_amdgcn_mfma_f32_16x16x32_f16(fAh[i], fBh[j], acc[i][j], 0, 0, 0);
                    acc[i][j] = __builtin_amdgcn_mfma_f32_16x16x32_f16(fAh[i], fBl[j], acc[i][j], 0, 0, 0);
                    acc[i][j] = __builtin_amdgcn_mfma_f32_16x16x32_f16(fAl[i], fBh[j], acc[i][j], 0, 0, 0);
                }
            __syncthreads();
        }
    }

    float eta = 0.f, thr = 0.f;
    if (epi == ME_FISTAG || epi == ME_FISTAG_LAST) { eta = scal[1]; thr = scal[2]; }
    float rsq = 0.f;
    #pragma unroll
    for (int i = 0; i < AI; ++i) {
        int grow0 = row0 + wr * WTR + i * 16 + quad * 4;
        bool rowok = grow0 < Mvalid;
        #pragma unroll
        for (int j = 0; j < BJ; ++j) {
            int gcol = col0 + wc * WTC + j * 16 + lc;
            bool colok = gcol < Nvalid;
            floatx4_t v = acc[i][j];
            if (epi == ME_STORE) {
                if (rowok && colok) {
                    #pragma unroll
                    for (int r2 = 0; r2 < 4; ++r2) C[(size_t)(grow0 + r2) * ldc + gcol] = v[r2];
                }
            } else if (epi == ME_SYMSPLIT || epi == ME_SYMSPLIT_MI || epi == ME_H1 ||
                       epi == ME_SYMSPLIT16) {
                #pragma unroll
                for (int r2 = 0; r2 < 4; ++r2) {
                    float vv = v[r2];
                    float dg = ((grow0 + r2) == gcol) ? 1.f : 0.f;
                    size_t o = (size_t)(grow0 + r2) * Tstride + gcol;
                    if (epi == ME_SYMSPLIT_MI) {
                        vv -= dg;                        // E = G - I
                    } else if (epi == ME_H1) {
                        // H1 = (Eh·E + 2E + I)/16 ≈ G^2/16 ; E re-read from A operand
                        float ev = (float)Ah[o] + (float)Al[o];
                        vv = (vv + 2.f * ev + dg) * 0.0625f;
                    } else if (epi == ME_SYMSPLIT16) {
                        vv *= 16.f;                      // H5 = 16·H4^2, keeps f16-normal range
                    }
                    _Float16 h = (_Float16)vv;
                    Th[o] = h;
                    Tl[o] = (_Float16)(vv - (float)h);
                }
            } else if (epi == ME_SPLIT_T) {
                if (rowok && colok) {
                    half4_t hh, ll;
                    #pragma unroll
                    for (int r2 = 0; r2 < 4; ++r2) {
                        _Float16 h = (_Float16)v[r2];
                        hh[r2] = h; ll[r2] = (_Float16)(v[r2] - (float)h);
                    }
                    size_t to = (size_t)gcol * Tstride + grow0;
                    *reinterpret_cast<half4_t*>(&Th[to]) = hh;
                    *reinterpret_cast<half4_t*>(&Tl[to]) = ll;
                }
            } else if (epi == ME_FISTAG || epi == ME_FISTAG_LAST) {
                // SWAPPED operands: rows = n (NF), cols = m (MD). A operand = Z_in.
                // Zt_in/Zt_out/BmT/GammaT all row-major [n][m] at the SAME index ->
                // fully coalesced across lanes. acc = (Z^T E)[n][m] = (EZ)[m][n].
                #pragma unroll
                for (int r2 = 0; r2 < 4; ++r2) {
                    size_t idx = (size_t)(grow0 + r2) * (size_t)Tstride + gcol;
                    float z = (float)Ah[idx] + (float)Al[idx];
                    float p = v[r2] + z;                          // GZ at (m,n)
                    float bi = BmP[idx];
                    rsq = fmaf(z, p - 2.0f * bi, rsq);           // <Z,GZ> - 2<Z,B>
                    float g = z - eta * (p - bi);
                    float gn = softt(g, thr);
                    float zo;
                    if (epi == ME_FISTAG) {
                        float gold = C[idx];                      // GammaT[n][m]
                        C[idx] = gn;
                        zo = gn + betak * (gn - gold);
                    } else {
                        // final iter: write Gamma in required [MD][NF] layout (once)
                        C[(size_t)gcol * NF_ + (grow0 + r2)] = gn;
                        zo = gn;
                    }
                    _Float16 h = (_Float16)zo;
                    Th[idx] = h;
                    Tl[idx] = (_Float16)(zo - (float)h);
                }
            } else {   // ME_BIAS / ME_BIASRELU
                if (rowok && colok) {
                    #pragma unroll
                    for (int r2 = 0; r2 < 4; ++r2) {
                        float s = v[r2] + bias[gcol];
                        if (epi == ME_BIASRELU) s = s > 0.f ? s : 0.f;
                        C[(size_t)(grow0 + r2) * ldc + gcol] = s;
                    }
                }
            }
        }
    }
    if (epi == ME_FISTAG || epi == ME_FISTAG_LAST) {
        float tot = blockReduceSum(rsq, red);
        if (tid == 0) atomicAdd(nrm_acc, tot);
    }
}

__global__ void logsoftmax_kernel(const float* __restrict__ O, float* __restrict__ out) {
    int row = blockIdx.x * 4 + (threadIdx.x >> 6);
    int lane = threadIdx.x & 63;
    if (row >= NN_) return;
    float v = O[row * NC_ + lane];
    float m = v;
    #pragma unroll
    for (int off = 32; off; off >>= 1) m = fmaxf(m, __shfl_xor(m, off));
    float e = expf(v - m);
    float s = e;
    #pragma unroll
    for (int off = 32; off; off >>= 1) s += __shfl_xor(s, off);
    out[row * NC_ + lane] = (v - m) - logf(s);
}

__global__ void norms_kernel(const float* __restrict__ scal, float* __restrict__ nout) {
    int k = threadIdx.x;
    if (k < FITER) {
        float ysq = scal[4];
        float v = scal[5 + k] + ysq;            // ||WZ-Y||^2 via Gram identity
        nout[k] = sqrtf(fmaxf(v, 0.f)) / sqrtf(ysq);
    }
}

static inline void launch_m(int mode, dim3 grid,
                            const _Float16* Ah, const _Float16* Al,
                            const float* Afp, int Marr,
                            const _Float16* Bh, const _Float16* Bl,
                            int K, int Mvalid, int Nvalid, int ldc,
                            float* C, const float* BmP, const float* bias,
                            _Float16* Th, _Float16* Tl, int Tstride,
                            const float* scal, float betak, float* nrm, int epi,
                            hipStream_t s) {
    switch (mode) {
    case MO_BHL:
        mgemm_kernel<MO_BHL><<<grid, dim3(512), 0, s>>>(
            Ah, Al, Afp, Marr, Bh, Bl, K, Mvalid, Nvalid, ldc, C, BmP, bias,
            Th, Tl, Tstride, scal, betak, nrm, epi);
        break;
    case MO_AHL:
        mgemm_kernel<MO_AHL><<<grid, dim3(512), 0, s>>>(
            Ah, Al, Afp, Marr, Bh, Bl, K, Mvalid, Nvalid, ldc, C, BmP, bias,
            Th, Tl, Tstride, scal, betak, nrm, epi);
        break;
    case MO_THREE:
        mgemm_kernel<MO_THREE><<<grid, dim3(512), 0, s>>>(
            Ah, Al, Afp, Marr, Bh, Bl, K, Mvalid, Nvalid, ldc, C, BmP, bias,
            Th, Tl, Tstride, scal, betak, nrm, epi);
        break;
    default:
        mgemm_kernel<MO_AFP32><<<grid, dim3(512), 0, s>>>(
            Ah, Al, Afp, Marr, Bh, Bl, K, Mvalid, Nvalid, ldc, C, BmP, bias,
            Th, Tl, Tstride, scal, betak, nrm, epi);
        break;
    }
}

extern "C" void kernel_launch(void* const* d_in, const int* in_sizes, int n_in,
                              void* d_out, int out_size, void* d_ws, size_t ws_size,
                              hipStream_t stream) {
    const float* x     = (const float*)d_in[0];   // (2708, 4096)
    const float* adj   = (const float*)d_in[1];   // (2708, 2708)
    const float* gc1_w = (const float*)d_in[2];   // (4096, 1024)
    const float* gc1_b = (const float*)d_in[3];   // (1024,)
    const float* gc2_w = (const float*)d_in[4];   // (1024, 64)
    const float* gc2_b = (const float*)d_in[5];   // (64,)
    const float* Wd    = (const float*)d_in[6];   // (2708, 2048)
    const int*   Kp    = (const int*)d_in[7];     // scalar K

    float* out = (float*)d_out;
    float* logp    = out;                                     // (2708, 64)
    float* x_dec   = logp + (size_t)NN_ * NC_;                // (2708, 4096)
    float* Gamma   = x_dec + (size_t)NN_ * NF_;               // (2048, 4096) final layout
    float* norms_o = Gamma + (size_t)MD_ * NF_;               // (20,)
    // During FISTA iters 0..18 the Gamma slab holds GammaT [4096][2048] (same bytes);
    // the LAST iteration writes the required [2048][4096] layout directly.
    float* GammaT = Gamma;

    // ---- ws layout: 100,679,808 B (same proven footprint) ----
    char* wsb = (char*)d_ws;
    const size_t OFF_R1 = 16512;                       // after scal/Xa/Xb
    const size_t OFF_R2 = OFF_R1 + 16777216;           // Eh/El (16.78 MB)
    const size_t OFF_R3 = OFF_R2 + 33554432;           // BmT (33.55 MB)
    const size_t OFF_R4 = OFF_R3 + 33554432;           // Wt+xth -> H chain -> ZtA
    float* scal = (float*)wsb;
    float* Xa   = scal + 32;
    float* Xb   = Xa + MD_;
    _Float16* Eh = (_Float16*)(wsb + OFF_R1);          // E = G - I, split
    _Float16* El = Eh + (size_t)MD_ * MD_;
    float* BmT = (float*)(wsb + OFF_R2);               // B^T = (W^T Y)^T, [4096][2048] fp32
    // R3 phase 1: Wt + xth_hi
    _Float16* Wt_hi  = (_Float16*)(wsb + OFF_R3);
    _Float16* Wt_lo  = Wt_hi + (size_t)MD_ * KPAD;
    _Float16* xth_hi = Wt_lo + (size_t)MD_ * KPAD;     // 11.14 MB, fits slack
    _Float16* xth_lo = (_Float16*)(wsb + OFF_R4);      // R4 phase 1 (11.14 <= 16.78)
    // H squaring chain ping-pong: HA in R4 (16.78 MB), HB in first 16.78 MB of R3
    _Float16* HA_hi = (_Float16*)(wsb + OFF_R4);
    _Float16* HA_lo = HA_hi + (size_t)MD_ * MD_;
    _Float16* HB_hi = (_Float16*)(wsb + OFF_R3);
    _Float16* HB_lo = HB_hi + (size_t)MD_ * MD_;
    // R3 phase 2: ZtA (4096 x 2048 split, ping) — after power consumes H5 (in HA)
    _Float16* ZA_hi = (_Float16*)(wsb + OFF_R3);
    _Float16* ZA_lo = ZA_hi + (size_t)NF_ * MD_;
    // pong: the x_dec slab of d_out (44.4 MB >= 33.55 MB), scratch until phase 3
    _Float16* ZB_hi = (_Float16*)x_dec;
    _Float16* ZB_lo = ZB_hi + (size_t)NF_ * MD_;
    // phase 3:
    _Float16* adjT_hi = (_Float16*)(wsb + OFF_R2);                 // [2816][2720] hi, 15.3 MB
    _Float16* xwT_hi  = (_Float16*)(wsb + OFF_R2 + 15319040);      // [1024][2720] split, 11.1 MB
    _Float16* xwT_lo  = xwT_hi + (size_t)NH_ * KPAD;
    _Float16* g1t_hi  = (_Float16*)(wsb + OFF_R1);                 // [1024][4096] split
    _Float16* g1t_lo  = g1t_hi + (size_t)NH_ * NF_;
    _Float16* xdh     = (_Float16*)(wsb + OFF_R3);                 // [2816][4096] hi, 23.1 MB
    float*    hbuf    = (float*)(wsb + OFF_R3);                    // [2708][1024] fp32 (after xdh dead)
    _Float16* Wh      = (_Float16*)(wsb + OFF_R4);                 // [2816][2048] hi, 11.5 MB
    _Float16* g2t_hi  = (_Float16*)(wsb + OFF_R4 + 11534336);      // [128][1024] split
    _Float16* g2t_lo  = g2t_hi + (size_t)128 * NH_;
    _Float16* hwT_hi  = (_Float16*)(wsb + OFF_R4 + 12058624);      // [128][2720] split
    _Float16* hwT_lo  = hwT_hi + (size_t)128 * KPAD;
    float*    obuf    = (float*)(wsb + OFF_R4 + 13451264);         // [2708][64]

    const _Float16* nullh = nullptr;
    float* nullf = nullptr;

    // ---- phase 1: init, E = W^T W - I, B^T = (W^T Y)^T, squaring chain, power, Gamma0 ----
    zero_scal_kernel<<<1, 64, 0, stream>>>(scal);
    init_x0_kernel<<<4, 256, 0, stream>>>(Xa);
    sumsq_kernel<<<1024, 256, 0, stream>>>(x, NN_ * NF_, scal + 4);

    tsplit_kernel<<<dim3(MD_ / 32, KPAD / 32), 256, 0, stream>>>(Wd, NN_, MD_, KPAD, Wt_hi, Wt_lo);
    // E = W^T W - I (3-product: E is the 24x-applied operator, keep full precision)
    launch_m(MO_THREE, dim3(16, 16), Wt_hi, Wt_lo, nullptr, 0, Wt_hi, Wt_lo,
             KPAD, MD_, MD_, 0, nullf, nullptr, nullptr, Eh, El, MD_,
             scal, 0.f, nullptr, ME_SYMSPLIT_MI, stream);
    // BmT[n][m] = sum_k Y[k][n] W[k][m], SWAPPED (A = Y^T hi/lo, B = Wt hi):
    // products Yh·Wh + Yl·Wh — identical scalar set to the old Wh·Yh + Wh·Yl (commuted).
    for (int half = 0; half < 2; ++half) {
        tsplit_kernel<<<dim3(MD_ / 32, KPAD / 32), 256, 0, stream>>>(
            x + half * 2048, NN_, NF_, KPAD, xth_hi, xth_lo);
        launch_m(MO_AHL, dim3(16, 16), xth_hi, xth_lo, nullptr, 0, Wt_hi, Wt_lo,
                 KPAD, 2048, MD_, MD_, BmT + (size_t)half * 2048 * MD_, nullptr, nullptr,
                 nullptr, nullptr, 0, scal, 0.f, nullptr, ME_STORE, stream);
    }
    // squaring chain (2-product): H1=G^2/16, H2=H1^2, H3=H2^2, H4=H3^2, H5=16*H4^2 (=G^32/2^60)
    launch_m(MO_BHL, dim3(16, 16), Eh, El, nullptr, 0, Eh, El,
             MD_, MD_, MD_, 0, nullf, nullptr, nullptr, HA_hi, HA_lo, MD_,
             scal, 0.f, nullptr, ME_H1, stream);
    launch_m(MO_BHL, dim3(16, 16), HA_hi, HA_lo, nullptr, 0, HA_hi, HA_lo,
             MD_, MD_, MD_, 0, nullf, nullptr, nullptr, HB_hi, HB_lo, MD_,
             scal, 0.f, nullptr, ME_SYMSPLIT, stream);
    launch_m(MO_BHL, dim3(16, 16), HB_hi, HB_lo, nullptr, 0, HB_hi, HB_lo,
             MD_, MD_, MD_, 0, nullf, nullptr, nullptr, HA_hi, HA_lo, MD_,
             scal, 0.f, nullptr, ME_SYMSPLIT, stream);
    launch_m(MO_BHL, dim3(16, 16), HA_hi, HA_lo, nullptr, 0, HA_hi, HA_lo,
             MD_, MD_, MD_, 0, nullf, nullptr, nullptr, HB_hi, HB_lo, MD_,
             scal, 0.f, nullptr, ME_SYMSPLIT, stream);
    launch_m(MO_BHL, dim3(16, 16), HB_hi, HB_lo, nullptr, 0, HB_hi, HB_lo,
             MD_, MD_, MD_, 0, nullf, nullptr, nullptr, HA_hi, HA_lo, MD_,
             scal, 0.f, nullptr, ME_SYMSPLIT16, stream);
    // power: 3x H5 + 4x G (= exactly 100 G-applies), plain launches, stream-ordered.
    for (int it = 0; it < 7; ++it) {
        const _Float16* mh = (it < 3) ? HA_hi : Eh;
        const _Float16* ml = (it < 3) ? HA_lo : El;
        const float* xin = (it & 1) ? Xb : Xa;
        float* xout = (it & 1) ? Xa : Xb;
        papply_kernel<<<MD_ / 4, 256, 0, stream>>>(mh, ml, xin, xout, (it >= 3) ? 1 : 0);
    }
    pfinal_kernel<<<1, 256, 0, stream>>>(Xb, Kp, scal);
    // Gamma0: elementwise over [NF][MD] — GammaT + Zt split, all coalesced (HB dead now)
    g0_kernel<<<(NF_ * MD_ / 4) / 256, 256, 0, stream>>>(BmT, scal, GammaT, ZA_hi, ZA_lo);

    // ---- phase 2: FISTA in Gram domain, SWAPPED: A = Z^T (hi/lo), B = E (symmetric) ----
    // out[n][m] = sum_k Zt[n][k] E[k][m]; epilogue buffers all row-major [n][m].
    {
        float t = 1.f;
        for (int k = 0; k < FITER; ++k) {
            float tn = (1.0f + sqrtf(1.0f + (4.0f * t) * t)) / 2.0f;
            float beta = (t - 1.0f) / tn;
            t = tn;
            _Float16* in_hi  = (k & 1) ? ZB_hi : ZA_hi;
            _Float16* in_lo  = (k & 1) ? ZB_lo : ZA_lo;
            _Float16* out_hi = (k & 1) ? ZA_hi : ZB_hi;
            _Float16* out_lo = (k & 1) ? ZA_lo : ZB_lo;
            launch_m(MO_AHL, dim3(MD_ / 128, NF_ / 128), in_hi, in_lo, nullptr, 0, Eh, El,
                     MD_, NF_, MD_, NF_, GammaT, BmT, nullptr,
                     out_hi, out_lo, MD_, scal, beta, scal + 5 + k,
                     (k == FITER - 1) ? ME_FISTAG_LAST : ME_FISTAG, stream);
        }
        // FITER=20 even: final Zt lands in ZA (ws); LAST wrote Gamma in final layout.
    }

    // ---- phase 3: decode + GCN tail (all 2-product staged MFMA) ----
    splitadj_hi_kernel<<<2816, 256, 0, stream>>>(adj, adjT_hi);        // BmT dead now
    splitrows_hi_kernel<<<2816, 256, 0, stream>>>(Wd, NN_, MD_, Wh);
    // x_dec = W @ Gamma : A = Wh (2-product), B = ZA (Gamma^T split)
    launch_m(MO_BHL, dim3(32, 22), Wh, Wh, nullptr, 0, ZA_hi, ZA_lo,
             MD_, NN_, NF_, NF_, x_dec, nullptr, nullptr,
             nullptr, nullptr, 0, scal, 0.f, nullptr, ME_STORE, stream);
    // xdh = hi(x_dec), overwrites dead ZA
    splitrows_hi_kernel<<<2816, 256, 0, stream>>>(x_dec, NN_, NF_, xdh);
    tsplit_kernel<<<dim3(NH_ / 32, NF_ / 32), 256, 0, stream>>>(gc1_w, NF_, NH_, NF_, g1t_hi, g1t_lo);
    fill0_kernel<<<(2785280 + 255) / 256, 256, 0, stream>>>((uint32_t*)xwT_hi, 2785280);
    // xw^T = split((x_dec @ gc1_w)^T) : A = xdh (2-product)
    launch_m(MO_BHL, dim3(8, 22), xdh, xdh, nullptr, 0, g1t_hi, g1t_lo,
             NF_, NN_, NH_, 0, nullf, nullptr, nullptr,
             xwT_hi, xwT_lo, KPAD, scal, 0.f, nullptr, ME_SPLIT_T, stream);
    // h = relu(adj @ xw + b1) : A = adjT_hi (2-product); hbuf overwrites dead xdh
    launch_m(MO_BHL, dim3(8, 22), adjT_hi, adjT_hi, nullptr, 0, xwT_hi, xwT_lo,
             KPAD, NN_, NH_, NH_, hbuf, nullptr, gc1_b,
             nullptr, nullptr, 0, scal, 0.f, nullptr, ME_BIASRELU, stream);
    fill0_kernel<<<(131072 + 255) / 256, 256, 0, stream>>>((uint32_t*)g2t_hi, 131072);
    tsplit_kernel<<<dim3(NC_ / 32, NH_ / 32), 256, 0, stream>>>(gc2_w, NH_, NC_, NH_, g2t_hi, g2t_lo);
    fill0_kernel<<<(348160 + 255) / 256, 256, 0, stream>>>((uint32_t*)hwT_hi, 348160);
    // hw^T = split((h @ gc2_w)^T) : tiny, keep AFP32 3-product
    launch_m(MO_AFP32, dim3(1, 22), nullh, nullh, hbuf, NN_, g2t_hi, g2t_lo,
             NH_, NN_, NC_, 0, nullf, nullptr, nullptr,
             hwT_hi, hwT_lo, KPAD, scal, 0.f, nullptr, ME_SPLIT_T, stream);
    // o = adj @ hw + b2 : A = adjT_hi (2-product)
    launch_m(MO_BHL, dim3(1, 22), adjT_hi, adjT_hi, nullptr, 0, hwT_hi, hwT_lo,
             KPAD, NN_, NC_, NC_, obuf, nullptr, gc2_b,
             nullptr, nullptr, 0, scal, 0.f, nullptr, ME_BIAS, stream);
    logsoftmax_kernel<<<(NN_ + 3) / 4, 256, 0, stream>>>(obuf, logp);
    norms_kernel<<<1, 32, 0, stream>>>(scal, norms_o);
}

// Round 12
// 2941.225 us; speedup vs baseline: 1.0475x; 1.0475x over previous
//
#include <hip/hip_runtime.h>
#include <cstdint>
#include <cmath>

#define NN_ 2708
#define NF_ 4096
#define MD_ 2048
#define NH_ 1024
#define NC_ 64
#define FITER 20
#define KPAD 2720   // 2708 padded to multiple of 32

// scal layout (floats in ws): [0]=c [1]=eta [2]=thr(lam/c) [3]=lam [4]=ynormsq [5..24]=rsq[k]

typedef _Float16 half8_t __attribute__((ext_vector_type(8)));
typedef _Float16 half4_t __attribute__((ext_vector_type(4)));
typedef float floatx4_t __attribute__((ext_vector_type(4)));

__device__ __forceinline__ float softt(float v, float t) {
    float a = fabsf(v) - t;
    a = a > 0.f ? a : 0.f;
    return copysignf(a, v);
}

// supports blockDim 256 or 512 (nw <= 8)
__device__ __forceinline__ float blockReduceSum(float v, float* red) {
    int lane = threadIdx.x & 63, wid = threadIdx.x >> 6;
    #pragma unroll
    for (int off = 32; off; off >>= 1) v += __shfl_down(v, off);
    if (lane == 0) red[wid] = v;
    __syncthreads();
    if (wid == 0) {
        int nw = (blockDim.x + 63) >> 6;
        float r = (lane < nw) ? red[lane] : 0.f;
        #pragma unroll
        for (int off = 4; off; off >>= 1) r += __shfl_down(r, off);
        if (lane == 0) red[0] = r;
    }
    __syncthreads();
    float out = red[0];
    __syncthreads();
    return out;
}

// ---------- threefry2x32 + JAX normal init ----------
__device__ __forceinline__ float erfinv_f(float x) {
    float w = -log1pf(-x * x);
    float p;
    if (w < 5.0f) {
        w -= 2.5f;
        p = 2.81022636e-08f;
        p = fmaf(p, w, 3.43273939e-07f);
        p = fmaf(p, w, -3.5233877e-06f);
        p = fmaf(p, w, -4.39150654e-06f);
        p = fmaf(p, w, 0.00021858087f);
        p = fmaf(p, w, -0.00125372503f);
        p = fmaf(p, w, -0.00417768164f);
        p = fmaf(p, w, 0.246640727f);
        p = fmaf(p, w, 1.50140941f);
    } else {
        w = sqrtf(w) - 3.0f;
        p = -0.000200214257f;
        p = fmaf(p, w, 0.000100950558f);
        p = fmaf(p, w, 0.00134934322f);
        p = fmaf(p, w, -0.00367342844f);
        p = fmaf(p, w, 0.00573950773f);
        p = fmaf(p, w, -0.0076224613f);
        p = fmaf(p, w, 0.00943887047f);
        p = fmaf(p, w, 1.00167406f);
        p = fmaf(p, w, 2.83297682f);
    }
    return p * x;
}

__device__ __forceinline__ float u32_to_normal(uint32_t bits) {
    uint32_t fb = (bits >> 9) | 0x3F800000u;
    float f = __uint_as_float(fb) - 1.0f;        // [0,1)
    const float lo = -0.99999994f;               // nextafter(-1,0) in f32
    float u = fmaf(f, 2.0f, lo);
    u = fmaxf(lo, u);
    return 1.41421356f * erfinv_f(u);
}

__global__ void init_x0_kernel(float* __restrict__ X0) {
    int i = blockIdx.x * blockDim.x + threadIdx.x;   // 0..1023 pairs
    if (i >= MD_ / 2) return;
    uint32_t x0 = (uint32_t)i, x1 = (uint32_t)(i + MD_ / 2);
    const uint32_t k0 = 0u, k1 = 1u, k2 = 0x1BD11BDBu;
    const uint32_t ks[3] = {k0, k1, k2};
    x0 += k0; x1 += k1;
    const int rot[8] = {13, 15, 26, 6, 17, 29, 16, 24};
    #pragma unroll
    for (int g = 0; g < 5; ++g) {
        const int base = (g & 1) ? 4 : 0;
        #pragma unroll
        for (int rr = 0; rr < 4; ++rr) {
            x0 += x1;
            int r = rot[base + rr];
            x1 = (x1 << r) | (x1 >> (32 - r));
            x1 ^= x0;
        }
        x0 += ks[(g + 1) % 3];
        x1 += ks[(g + 2) % 3] + (uint32_t)(g + 1);
    }
    X0[i] = u32_to_normal(x0);
    X0[i + MD_ / 2] = u32_to_normal(x1);
}

__global__ void zero_scal_kernel(float* __restrict__ scal) {
    int t = threadIdx.x;
    if (t < 32) scal[t] = 0.f;
}

__global__ void fill0_kernel(uint32_t* __restrict__ p, int n32) {
    int i = blockIdx.x * blockDim.x + threadIdx.x;
    if (i < n32) p[i] = 0u;
}

__global__ void sumsq_kernel(const float* __restrict__ X, int n, float* __restrict__ acc) {
    __shared__ float red[8];
    float s = 0.f;
    for (size_t i = (size_t)blockIdx.x * blockDim.x + threadIdx.x; i < (size_t)n;
         i += (size_t)gridDim.x * blockDim.x) {
        float v = X[i];
        s += v * v;
    }
    s = blockReduceSum(s, red);
    if (threadIdx.x == 0) atomicAdd(acc, s);
}

// ---------- transpose + split fp32 -> f16 hi/lo, out[c][r] padded to Rpad ----------
__global__ void tsplit_kernel(const float* __restrict__ src, int R, int ld, int Rpad,
                              _Float16* __restrict__ hi, _Float16* __restrict__ lo) {
    __shared__ float t[32][33];
    int rb = blockIdx.y * 32, cb = blockIdx.x * 32;
    int tx = threadIdx.x & 31, ty = threadIdx.x >> 5;   // ty 0..7
    #pragma unroll
    for (int s = 0; s < 32; s += 8) {
        int r = rb + ty + s, c = cb + tx;
        t[ty + s][tx] = (r < R) ? src[(size_t)r * ld + c] : 0.f;
    }
    __syncthreads();
    #pragma unroll
    for (int s = 0; s < 32; s += 8) {
        int c = cb + ty + s, r = rb + tx;
        float v = t[tx][ty + s];
        _Float16 h = (_Float16)v;
        size_t o = (size_t)c * Rpad + r;
        hi[o] = h;
        lo[o] = (_Float16)(v - (float)h);
    }
}

// ---------- fp32 -> f16 hi-only, non-transposed, zero row-padding ----------
// grid.x = Rpad, rows >= R write zeros; C multiple of 4
__global__ void splitrows_hi_kernel(const float* __restrict__ src, int R, int C,
                                    _Float16* __restrict__ hi) {
    int r = blockIdx.x;
    _Float16* d = hi + (size_t)r * C;
    if (r < R) {
        const float* s = src + (size_t)r * C;
        for (int c = threadIdx.x * 4; c < C; c += 1024) {
            float4 v = *reinterpret_cast<const float4*>(s + c);
            half4_t h;
            h[0] = (_Float16)v.x; h[1] = (_Float16)v.y;
            h[2] = (_Float16)v.z; h[3] = (_Float16)v.w;
            *reinterpret_cast<half4_t*>(d + c) = h;
        }
    } else {
        for (int c = threadIdx.x * 4; c < C; c += 1024) {
            half4_t h = {(_Float16)0.f, (_Float16)0.f, (_Float16)0.f, (_Float16)0.f};
            *reinterpret_cast<half4_t*>(d + c) = h;
        }
    }
}

// ---------- adj -> f16 hi-only, [2816][2720] zero-padded (2708 % 4 == 0) ----------
__global__ void splitadj_hi_kernel(const float* __restrict__ adj, _Float16* __restrict__ hi) {
    int r = blockIdx.x;   // 0..2815
    bool rok = r < NN_;
    _Float16* d = hi + (size_t)r * KPAD;
    const float* s = adj + (size_t)r * NN_;
    for (int c = threadIdx.x * 4; c < KPAD; c += 1024) {
        half4_t h = {(_Float16)0.f, (_Float16)0.f, (_Float16)0.f, (_Float16)0.f};
        if (rok && c + 3 < NN_) {
            float4 v = *reinterpret_cast<const float4*>(s + c);
            h[0] = (_Float16)v.x; h[1] = (_Float16)v.y;
            h[2] = (_Float16)v.z; h[3] = (_Float16)v.w;
        }
        *reinterpret_cast<half4_t*>(d + c) = h;
    }
}

// ---------- Gamma0 = soft(eta*B, lam); Zt = split(Gamma0^T) ----------
__global__ void g0_kernel(const float* __restrict__ Bm, const float* __restrict__ scal,
                          float* __restrict__ Gamma,
                          _Float16* __restrict__ Zh, _Float16* __restrict__ Zl) {
    __shared__ float t[32][33];
    int rb = blockIdx.y * 32;   // m-dim (2048)
    int cb = blockIdx.x * 32;   // nfeat (4096)
    float eta = scal[1], lam = scal[3];
    int tx = threadIdx.x & 31, ty = threadIdx.x >> 5;
    #pragma unroll
    for (int s = 0; s < 32; s += 8) {
        int r = rb + ty + s, c = cb + tx;
        float g = softt(eta * Bm[(size_t)r * NF_ + c], lam);
        Gamma[(size_t)r * NF_ + c] = g;
        t[ty + s][tx] = g;
    }
    __syncthreads();
    #pragma unroll
    for (int s = 0; s < 32; s += 8) {
        int c = cb + ty + s, r = rb + tx;
        float v = t[tx][ty + s];
        _Float16 h = (_Float16)v;
        size_t o = (size_t)c * MD_ + r;
        Zh[o] = h;
        Zl[o] = (_Float16)(v - (float)h);
    }
}

// ---------- power step, NON-cooperative: one plain launch per apply ----------
__global__ __launch_bounds__(256)
void papply_kernel(const _Float16* __restrict__ Mh, const _Float16* __restrict__ Ml,
                   const float* __restrict__ Xc, float* __restrict__ Xn, int addI) {
    __shared__ float xs[MD_];
    __shared__ float red[8];
    const int tid = threadIdx.x;
    float ss = 0.f;
    for (int k = tid; k < MD_; k += 256) { float v = Xc[k]; xs[k] = v; ss += v * v; }
    __syncthreads();
    ss = blockReduceSum(ss, red);
    float inv = 1.0f / sqrtf(ss);
    const int w = tid >> 6, l = tid & 63;
    const int r = blockIdx.x * 4 + w;
    const _Float16* mhr = Mh + (size_t)r * MD_;
    const _Float16* mlr = Ml + (size_t)r * MD_;
    float s = 0.f;
    #pragma unroll
    for (int q = 0; q < 8; ++q) {
        int o = (q * 64 + l) * 4;
        half4_t hv = *reinterpret_cast<const half4_t*>(mhr + o);
        half4_t lv = *reinterpret_cast<const half4_t*>(mlr + o);
        float4 xv = *reinterpret_cast<const float4*>(&xs[o]);
        s = fmaf((float)hv[0] + (float)lv[0], xv.x, s);
        s = fmaf((float)hv[1] + (float)lv[1], xv.y, s);
        s = fmaf((float)hv[2] + (float)lv[2], xv.z, s);
        s = fmaf((float)hv[3] + (float)lv[3], xv.w, s);
    }
    #pragma unroll
    for (int off = 32; off; off >>= 1) s += __shfl_down(s, off);
    if (l == 0) Xn[r] = (s + (addI ? xs[r] : 0.f)) * inv;
}

// ---------- finalize: c = ||Xf||, eta, thr ----------
__global__ void pfinal_kernel(const float* __restrict__ Xf, const int* __restrict__ Kp,
                              float* __restrict__ scal) {
    __shared__ float red[8];
    float ss = 0.f;
    for (int k = threadIdx.x; k < MD_; k += 256) { float v = Xf[k]; ss += v * v; }
    ss = blockReduceSum(ss, red);
    if (threadIdx.x == 0) {
        float c = sqrtf(ss);
        float lam = (float)Kp[0];
        scal[0] = c;
        scal[1] = 1.0f / c;
        scal[2] = lam / c;
        scal[3] = lam;
    }
}

// ---------- split-f16 MFMA GEMM, 128x128 tile, BK=32, 512 threads (8 waves 2x4) ----------
// LDS tiles [128][32] f16, XOR-swizzled (chunk ^= (row>>1)&3) on both the DMA source and the
// ds_read address -> bank-conflict-free (verified: SQ_LDS_BANK_CONFLICT 8.4M -> 0).
// f16 paths: 3-buffer depth-2 pipeline, COUNTED vmcnt across raw s_barrier (T4) — loads for
// tile t+2 stay in flight across the barrier; never drain to 0 in the main loop.
// Workgroup mapping: IDENTITY (round-5 lesson: XCD row-chunk swizzle destroyed B-column
// L2 reuse; round-11 lesson: operand-swap for epilogue coalescing raised FETCH 158->247 MB —
// the original orientation's streaming locality is the best measured).
enum { ME_STORE = 0, ME_SYMSPLIT = 1, ME_SYMSPLIT_MI = 2, ME_H1 = 3, ME_SYMSPLIT16 = 4,
       ME_SPLIT_T = 5, ME_FISTAG = 6, ME_FISTAG_LAST = 7, ME_BIAS = 8, ME_BIASRELU = 9 };

// 512 threads: each thread issues exactly one 16B global_load_lds chunk (128x32 f16 = 8KB)
__device__ __forceinline__ void stage_h(const _Float16* __restrict__ g, int row0, int K, int kk,
                                        _Float16* s, int tid) {
    const int row = tid >> 2;
    const int kg = (tid & 3) ^ ((row >> 1) & 3);        // inverse-swizzled source chunk
    const _Float16* gp = g + (size_t)(row0 + row) * K + kk + (kg << 3);
    _Float16* lp = s + ((size_t)((tid >> 6) * 64) << 3);   // wave-uniform base, lane*16B auto
    __builtin_amdgcn_global_load_lds(
        (const __attribute__((address_space(1))) void*)gp,
        (__attribute__((address_space(3))) void*)lp, 16, 0, 0);
}

template <bool AFP32, bool THREE>
__global__ __launch_bounds__(512)
void mgemm_kernel(const _Float16* __restrict__ Ah, const _Float16* __restrict__ Al,
                  const float* __restrict__ Afp, int Marr,
                  const _Float16* __restrict__ Bh, const _Float16* __restrict__ Bl,
                  int K, int Mvalid, int Nvalid, int ldc,
                  float* __restrict__ C, const float* __restrict__ BmP,
                  const float* __restrict__ bias,
                  _Float16* __restrict__ Th, _Float16* __restrict__ Tl, int Tstride,
                  const float* __restrict__ scal, float betak,
                  float* __restrict__ nrm_acc, int epi) {
    constexpr int TILE = 128 * 32;
    constexpr int TPB = THREE ? 4 : 3;                  // tiles per pipeline buffer
    constexpr int NT = AFP32 ? 4 : 3 * TPB;             // 32 / 96 / 72 KB
    __shared__ __align__(16) _Float16 smem[NT * TILE];
    float* red = (float*)smem;                          // epilogue-only alias (LDS dead then)
    const int tid = threadIdx.x;
    const int w = tid >> 6, l = tid & 63;
    const int wr = w >> 2, wc = w & 3;                  // 2x4 wave grid; wave tile 64x32
    const int quad = l >> 4, lc = l & 15;
    const int row0 = blockIdx.y * 128, col0 = blockIdx.x * 128;

    const int qs = (quad ^ ((lc >> 1) & 3)) << 3;       // swizzled chunk (row bases mult of 16)

    floatx4_t acc[4][2];
    #pragma unroll
    for (int i = 0; i < 4; ++i)
        #pragma unroll
        for (int j = 0; j < 2; ++j) {
            floatx4_t z = {0.f, 0.f, 0.f, 0.f};
            acc[i][j] = z;
        }

    if constexpr (!AFP32) {
        const int NTK = K >> 5;                         // K-tiles
        auto STAGE = [&](int kt, int b) {
            _Float16* base = smem + b * (TPB * TILE);
            stage_h(Ah, row0, K, kt << 5, base, tid);
            if constexpr (THREE) stage_h(Al, row0, K, kt << 5, base + TILE, tid);
            stage_h(Bh, col0, K, kt << 5, base + (THREE ? 2 : 1) * TILE, tid);
            stage_h(Bl, col0, K, kt << 5, base + (THREE ? 3 : 2) * TILE, tid);
        };
        // prologue: stage tiles 0,1 into bufs 0,1; wait tile0 only (counted)
        STAGE(0, 0);
        if (NTK > 1) {
            STAGE(1, 1);
            if constexpr (THREE) asm volatile("s_waitcnt vmcnt(4)" ::: "memory");
            else                 asm volatile("s_waitcnt vmcnt(3)" ::: "memory");
        } else {
            asm volatile("s_waitcnt vmcnt(0)" ::: "memory");
        }
        __builtin_amdgcn_s_barrier();
        for (int t = 0; t < NTK; ++t) {
            const int cur = t % 3;
            if (t + 2 < NTK) STAGE(t + 2, (t + 2) % 3);   // issue depth-2 prefetch (no wait)
            const _Float16* base = smem + cur * (TPB * TILE);
            const _Float16* pAh = base;
            const _Float16* pAl = base + TILE;                       // THREE only
            const _Float16* pBh = base + (THREE ? 2 : 1) * TILE;
            const _Float16* pBl = base + (THREE ? 3 : 2) * TILE;
            half8_t fAh[4], fAl[4], fBh[2], fBl[2];
            #pragma unroll
            for (int i = 0; i < 4; ++i) {
                int oa = (wr * 64 + i * 16 + lc) * 32 + qs;
                fAh[i] = *reinterpret_cast<const half8_t*>(&pAh[oa]);
                if constexpr (THREE) fAl[i] = *reinterpret_cast<const half8_t*>(&pAl[oa]);
            }
            #pragma unroll
            for (int j = 0; j < 2; ++j) {
                int ob = (wc * 32 + j * 16 + lc) * 32 + qs;
                fBh[j] = *reinterpret_cast<const half8_t*>(&pBh[ob]);
                fBl[j] = *reinterpret_cast<const half8_t*>(&pBl[ob]);
            }
            #pragma unroll
            for (int i = 0; i < 4; ++i)
                #pragma unroll
                for (int j = 0; j < 2; ++j) {
                    acc[i][j] = __builtin_amdgcn_mfma_f32_16x16x32_f16(fAh[i], fBh[j], acc[i][j], 0, 0, 0);
                    acc[i][j] = __builtin_amdgcn_mfma_f32_16x16x32_f16(fAh[i], fBl[j], acc[i][j], 0, 0, 0);
                    if constexpr (THREE)
                        acc[i][j] = __builtin_amdgcn_mfma_f32_16x16x32_f16(fAl[i], fBh[j], acc[i][j], 0, 0, 0);
                }
            // pin ds_read+MFMA before the barrier, then COUNTED wait: tile t+1's loads
            // (issued at t-1) must have landed; tile t+2's TPB loads may stay in flight.
            __builtin_amdgcn_sched_barrier(0);
            if (t + 2 < NTK) {
                if constexpr (THREE) asm volatile("s_waitcnt vmcnt(4)" ::: "memory");
                else                 asm volatile("s_waitcnt vmcnt(3)" ::: "memory");
            } else {
                asm volatile("s_waitcnt vmcnt(0)" ::: "memory");
            }
            __builtin_amdgcn_s_barrier();
        }
    } else {
        _Float16* sAh = smem;
        _Float16* sAl = smem + TILE;
        _Float16* sBh = smem + 2 * TILE;
        _Float16* sBl = smem + 3 * TILE;
        for (int kk = 0; kk < K; kk += 32) {
            #pragma unroll
            for (int p = 0; p < 2; ++p) {
                int c2 = p * 512 + tid;                 // 0..1023
                int r2 = c2 >> 3, k4 = (c2 & 7) << 2;
                int gr = row0 + r2;
                gr = gr < Marr ? gr : Marr - 1;         // clamp; masked at store
                float4 v = *reinterpret_cast<const float4*>(Afp + (size_t)gr * K + kk + k4);
                half4_t hh, ll;
                hh[0] = (_Float16)v.x; ll[0] = (_Float16)(v.x - (float)hh[0]);
                hh[1] = (_Float16)v.y; ll[1] = (_Float16)(v.y - (float)hh[1]);
                hh[2] = (_Float16)v.z; ll[2] = (_Float16)(v.z - (float)hh[2]);
                hh[3] = (_Float16)v.w; ll[3] = (_Float16)(v.w - (float)hh[3]);
                int sw = (((k4 >> 3) ^ ((r2 >> 1) & 3)) << 3) | (k4 & 7);   // swizzled write
                *reinterpret_cast<half4_t*>(&sAh[r2 * 32 + sw]) = hh;
                *reinterpret_cast<half4_t*>(&sAl[r2 * 32 + sw]) = ll;
            }
            stage_h(Bh, col0, K, kk, sBh, tid);
            stage_h(Bl, col0, K, kk, sBl, tid);
            asm volatile("s_waitcnt vmcnt(0)" ::: "memory");
            __syncthreads();

            half8_t fAh[4], fAl[4], fBh[2], fBl[2];
            #pragma unroll
            for (int i = 0; i < 4; ++i) {
                int oa = (wr * 64 + i * 16 + lc) * 32 + qs;
                fAh[i] = *reinterpret_cast<const half8_t*>(&sAh[oa]);
                fAl[i] = *reinterpret_cast<const half8_t*>(&sAl[oa]);
            }
            #pragma unroll
            for (int j = 0; j < 2; ++j) {
                int ob = (wc * 32 + j * 16 + lc) * 32 + qs;
                fBh[j] = *reinterpret_cast<const half8_t*>(&sBh[ob]);
                fBl[j] = *reinterpret_cast<const half8_t*>(&sBl[ob]);
            }
            #pragma unroll
            for (int i = 0; i < 4; ++i)
                #pragma unroll
                for (int j = 0; j < 2; ++j) {
                    acc[i][j] = __builtin_amdgcn_mfma_f32_16x16x32_f16(fAh[i], fBh[j], acc[i][j], 0, 0, 0);
                    acc[i][j] = __builtin_amdgcn_mfma_f32_16x16x32_f16(fAh[i], fBl[j], acc[i][j], 0, 0, 0);
                    acc[i][j] = __builtin_amdgcn_mfma_f32_16x16x32_f16(fAl[i], fBh[j], acc[i][j], 0, 0, 0);
                }
            __syncthreads();
        }
    }

    float eta = 0.f, thr = 0.f;
    if (epi == ME_FISTAG || epi == ME_FISTAG_LAST) { eta = scal[1]; thr = scal[2]; }
    float rsq = 0.f;
    #pragma unroll
    for (int i = 0; i < 4; ++i) {
        int grow0 = row0 + wr * 64 + i * 16 + quad * 4;
        bool rowok = grow0 < Mvalid;
        #pragma unroll
        for (int j = 0; j < 2; ++j) {
            int gcol = col0 + wc * 32 + j * 16 + lc;
            bool colok = gcol < Nvalid;
            floatx4_t v = acc[i][j];
            if (epi == ME_STORE) {
                if (rowok && colok) {
                    #pragma unroll
                    for (int r2 = 0; r2 < 4; ++r2) C[(size_t)(grow0 + r2) * ldc + gcol] = v[r2];
                }
            } else if (epi == ME_SYMSPLIT || epi == ME_SYMSPLIT_MI || epi == ME_H1 ||
                       epi == ME_SYMSPLIT16) {
                #pragma unroll
                for (int r2 = 0; r2 < 4; ++r2) {
                    float vv = v[r2];
                    float dg = ((grow0 + r2) == gcol) ? 1.f : 0.f;
                    size_t o = (size_t)(grow0 + r2) * Tstride + gcol;
                    if (epi == ME_SYMSPLIT_MI) {
                        vv -= dg;                        // E = G - I
                    } else if (epi == ME_H1) {
                        // H1 = (Eh·E + 2E + I)/16 ≈ G^2/16 ; E re-read from A operand
                        float ev = (float)Ah[o] + (float)Al[o];
                        vv = (vv + 2.f * ev + dg) * 0.0625f;
                    } else if (epi == ME_SYMSPLIT16) {
                        vv *= 16.f;                      // H5 = 16·H4^2, keeps f16-normal range
                    }
                    _Float16 h = (_Float16)vv;
                    Th[o] = h;
                    Tl[o] = (_Float16)(vv - (float)h);
                }
            } else if (epi == ME_SPLIT_T) {
                if (rowok && colok) {
                    half4_t hh, ll;
                    #pragma unroll
                    for (int r2 = 0; r2 < 4; ++r2) {
                        _Float16 h = (_Float16)v[r2];
                        hh[r2] = h; ll[r2] = (_Float16)(v[r2] - (float)h);
                    }
                    size_t to = (size_t)gcol * Tstride + grow0;
                    *reinterpret_cast<half4_t*>(&Th[to]) = hh;
                    *reinterpret_cast<half4_t*>(&Tl[to]) = ll;
                }
            } else if (epi == ME_FISTAG || epi == ME_FISTAG_LAST) {
                // A = E so acc = (EZ); GZ = acc + Z. Z_in read from B operand buffer,
                // Z_out -> Th/Tl (distinct ping-pong buffer, race-free)
                size_t to = (size_t)gcol * Tstride + grow0;
                half4_t zh = *reinterpret_cast<const half4_t*>(&Bh[to]);
                half4_t zl = *reinterpret_cast<const half4_t*>(&Bl[to]);
                half4_t oh, ol;
                #pragma unroll
                for (int r2 = 0; r2 < 4; ++r2) {
                    float z = (float)zh[r2] + (float)zl[r2];
                    float p = v[r2] + z;                          // GZ
                    float bi = BmP[(size_t)(grow0 + r2) * NF_ + gcol];
                    rsq = fmaf(z, p - 2.0f * bi, rsq);           // <Z,GZ> - 2<Z,B>
                    float g = z - eta * (p - bi);
                    float gn = softt(g, thr);
                    size_t ci = (size_t)(grow0 + r2) * NF_ + gcol;
                    float gold = C[ci];
                    C[ci] = gn;
                    float zo = (epi == ME_FISTAG) ? (gn + betak * (gn - gold)) : gn;
                    _Float16 h = (_Float16)zo;
                    oh[r2] = h; ol[r2] = (_Float16)(zo - (float)h);
                }
                *reinterpret_cast<half4_t*>(&Th[to]) = oh;
                *reinterpret_cast<half4_t*>(&Tl[to]) = ol;
            } else {   // ME_BIAS / ME_BIASRELU
                if (rowok && colok) {
                    #pragma unroll
                    for (int r2 = 0; r2 < 4; ++r2) {
                        float s = v[r2] + bias[gcol];
                        if (epi == ME_BIASRELU) s = s > 0.f ? s : 0.f;
                        C[(size_t)(grow0 + r2) * ldc + gcol] = s;
                    }
                }
            }
        }
    }
    if (epi == ME_FISTAG || epi == ME_FISTAG_LAST) {
        float tot = blockReduceSum(rsq, red);
        if (tid == 0) atomicAdd(nrm_acc, tot);
    }
}

__global__ void logsoftmax_kernel(const float* __restrict__ O, float* __restrict__ out) {
    int row = blockIdx.x * 4 + (threadIdx.x >> 6);
    int lane = threadIdx.x & 63;
    if (row >= NN_) return;
    float v = O[row * NC_ + lane];
    float m = v;
    #pragma unroll
    for (int off = 32; off; off >>= 1) m = fmaxf(m, __shfl_xor(m, off));
    float e = expf(v - m);
    float s = e;
    #pragma unroll
    for (int off = 32; off; off >>= 1) s += __shfl_xor(s, off);
    out[row * NC_ + lane] = (v - m) - logf(s);
}

__global__ void norms_kernel(const float* __restrict__ scal, float* __restrict__ nout) {
    int k = threadIdx.x;
    if (k < FITER) {
        float ysq = scal[4];
        float v = scal[5 + k] + ysq;            // ||WZ-Y||^2 via Gram identity
        nout[k] = sqrtf(fmaxf(v, 0.f)) / sqrtf(ysq);
    }
}

static inline void launch_m(bool afp32, bool three, dim3 grid,
                            const _Float16* Ah, const _Float16* Al,
                            const float* Afp, int Marr,
                            const _Float16* Bh, const _Float16* Bl,
                            int K, int Mvalid, int Nvalid, int ldc,
                            float* C, const float* BmP, const float* bias,
                            _Float16* Th, _Float16* Tl, int Tstride,
                            const float* scal, float betak, float* nrm, int epi,
                            hipStream_t s) {
    if (afp32)
        mgemm_kernel<true, true><<<grid, dim3(512), 0, s>>>(
            Ah, Al, Afp, Marr, Bh, Bl, K, Mvalid, Nvalid, ldc, C, BmP, bias,
            Th, Tl, Tstride, scal, betak, nrm, epi);
    else if (three)
        mgemm_kernel<false, true><<<grid, dim3(512), 0, s>>>(
            Ah, Al, Afp, Marr, Bh, Bl, K, Mvalid, Nvalid, ldc, C, BmP, bias,
            Th, Tl, Tstride, scal, betak, nrm, epi);
    else
        mgemm_kernel<false, false><<<grid, dim3(512), 0, s>>>(
            Ah, Al, Afp, Marr, Bh, Bl, K, Mvalid, Nvalid, ldc, C, BmP, bias,
            Th, Tl, Tstride, scal, betak, nrm, epi);
}

extern "C" void kernel_launch(void* const* d_in, const int* in_sizes, int n_in,
                              void* d_out, int out_size, void* d_ws, size_t ws_size,
                              hipStream_t stream) {
    const float* x     = (const float*)d_in[0];   // (2708, 4096)
    const float* adj   = (const float*)d_in[1];   // (2708, 2708)
    const float* gc1_w = (const float*)d_in[2];   // (4096, 1024)
    const float* gc1_b = (const float*)d_in[3];   // (1024,)
    const float* gc2_w = (const float*)d_in[4];   // (1024, 64)
    const float* gc2_b = (const float*)d_in[5];   // (64,)
    const float* Wd    = (const float*)d_in[6];   // (2708, 2048)
    const int*   Kp    = (const int*)d_in[7];     // scalar K

    float* out = (float*)d_out;
    float* logp    = out;                                     // (2708, 64)
    float* x_dec   = logp + (size_t)NN_ * NC_;                // (2708, 4096)
    float* Gamma   = x_dec + (size_t)NN_ * NF_;               // (2048, 4096)
    float* norms_o = Gamma + (size_t)MD_ * NF_;               // (20,)

    // ---- ws layout: 100,679,808 B (same proven footprint) ----
    char* wsb = (char*)d_ws;
    const size_t OFF_R1 = 16512;                       // after scal/Xa/Xb
    const size_t OFF_R2 = OFF_R1 + 16777216;           // Eh/El (16.78 MB)
    const size_t OFF_R3 = OFF_R2 + 33554432;           // Bm (33.55 MB)
    const size_t OFF_R4 = OFF_R3 + 33554432;           // Wt+xth -> H chain -> ZtA
    float* scal = (float*)wsb;
    float* Xa   = scal + 32;
    float* Xb   = Xa + MD_;
    _Float16* Eh = (_Float16*)(wsb + OFF_R1);          // E = G - I, split
    _Float16* El = Eh + (size_t)MD_ * MD_;
    float* Bm = (float*)(wsb + OFF_R2);
    // R3 phase 1: Wt + xth_hi
    _Float16* Wt_hi  = (_Float16*)(wsb + OFF_R3);
    _Float16* Wt_lo  = Wt_hi + (size_t)MD_ * KPAD;
    _Float16* xth_hi = Wt_lo + (size_t)MD_ * KPAD;     // 11.14 MB, fits slack
    _Float16* xth_lo = (_Float16*)(wsb + OFF_R4);      // R4 phase 1 (11.14 <= 16.78)
    // H squaring chain ping-pong: HA in R4 (16.78 MB), HB in first 16.78 MB of R3
    _Float16* HA_hi = (_Float16*)(wsb + OFF_R4);
    _Float16* HA_lo = HA_hi + (size_t)MD_ * MD_;
    _Float16* HB_hi = (_Float16*)(wsb + OFF_R3);
    _Float16* HB_lo = HB_hi + (size_t)MD_ * MD_;
    // R3 phase 2: ZtA (4096 x 2048 split, ping) — after power consumes H5 (in HA)
    _Float16* ZA_hi = (_Float16*)(wsb + OFF_R3);
    _Float16* ZA_lo = ZA_hi + (size_t)NF_ * MD_;
    // pong: the x_dec slab of d_out (44.4 MB >= 33.55 MB), scratch until phase 3
    _Float16* ZB_hi = (_Float16*)x_dec;
    _Float16* ZB_lo = ZB_hi + (size_t)NF_ * MD_;
    // phase 3:
    _Float16* adjT_hi = (_Float16*)(wsb + OFF_R2);                 // [2816][2720] hi, 15.3 MB
    _Float16* xwT_hi  = (_Float16*)(wsb + OFF_R2 + 15319040);      // [1024][2720] split, 11.1 MB
    _Float16* xwT_lo  = xwT_hi + (size_t)NH_ * KPAD;
    _Float16* g1t_hi  = (_Float16*)(wsb + OFF_R1);                 // [1024][4096] split
    _Float16* g1t_lo  = g1t_hi + (size_t)NH_ * NF_;
    _Float16* xdh     = (_Float16*)(wsb + OFF_R3);                 // [2816][4096] hi, 23.1 MB
    float*    hbuf    = (float*)(wsb + OFF_R3);                    // [2708][1024] fp32 (after xdh dead)
    _Float16* Wh      = (_Float16*)(wsb + OFF_R4);                 // [2816][2048] hi, 11.5 MB
    _Float16* g2t_hi  = (_Float16*)(wsb + OFF_R4 + 11534336);      // [128][1024] split
    _Float16* g2t_lo  = g2t_hi + (size_t)128 * NH_;
    _Float16* hwT_hi  = (_Float16*)(wsb + OFF_R4 + 12058624);      // [128][2720] split
    _Float16* hwT_lo  = hwT_hi + (size_t)128 * KPAD;
    float*    obuf    = (float*)(wsb + OFF_R4 + 13451264);         // [2708][64]

    const _Float16* nullh = nullptr;
    float* nullf = nullptr;

    // ---- phase 1: init, E = W^T W - I, B = W^T Y, squaring chain, power, Gamma0 ----
    zero_scal_kernel<<<1, 64, 0, stream>>>(scal);
    init_x0_kernel<<<4, 256, 0, stream>>>(Xa);
    sumsq_kernel<<<1024, 256, 0, stream>>>(x, NN_ * NF_, scal + 4);

    tsplit_kernel<<<dim3(MD_ / 32, KPAD / 32), 256, 0, stream>>>(Wd, NN_, MD_, KPAD, Wt_hi, Wt_lo);
    // E = W^T W - I (3-product: E is the 24x-applied operator, keep full precision)
    launch_m(false, true, dim3(16, 16), Wt_hi, Wt_lo, nullptr, 0, Wt_hi, Wt_lo,
             KPAD, MD_, MD_, 0, nullf, nullptr, nullptr, Eh, El, MD_,
             scal, 0.f, nullptr, ME_SYMSPLIT_MI, stream);
    // B = W^T Y in two N-halves (2-product: Wh·(Yh+Yl))
    for (int half = 0; half < 2; ++half) {
        tsplit_kernel<<<dim3(MD_ / 32, KPAD / 32), 256, 0, stream>>>(
            x + half * 2048, NN_, NF_, KPAD, xth_hi, xth_lo);
        launch_m(false, false, dim3(16, 16), Wt_hi, Wt_lo, nullptr, 0, xth_hi, xth_lo,
                 KPAD, MD_, MD_, NF_, Bm + half * 2048, nullptr, nullptr,
                 nullptr, nullptr, 0, scal, 0.f, nullptr, ME_STORE, stream);
    }
    // squaring chain (2-product): H1=G^2/16, H2=H1^2, H3=H2^2, H4=H3^2, H5=16*H4^2 (=G^32/2^60)
    launch_m(false, false, dim3(16, 16), Eh, El, nullptr, 0, Eh, El,
             MD_, MD_, MD_, 0, nullf, nullptr, nullptr, HA_hi, HA_lo, MD_,
             scal, 0.f, nullptr, ME_H1, stream);
    launch_m(false, false, dim3(16, 16), HA_hi, HA_lo, nullptr, 0, HA_hi, HA_lo,
             MD_, MD_, MD_, 0, nullf, nullptr, nullptr, HB_hi, HB_lo, MD_,
             scal, 0.f, nullptr, ME_SYMSPLIT, stream);
    launch_m(false, false, dim3(16, 16), HB_hi, HB_lo, nullptr, 0, HB_hi, HB_lo,
             MD_, MD_, MD_, 0, nullf, nullptr, nullptr, HA_hi, HA_lo, MD_,
             scal, 0.f, nullptr, ME_SYMSPLIT, stream);
    launch_m(false, false, dim3(16, 16), HA_hi, HA_lo, nullptr, 0, HA_hi, HA_lo,
             MD_, MD_, MD_, 0, nullf, nullptr, nullptr, HB_hi, HB_lo, MD_,
             scal, 0.f, nullptr, ME_SYMSPLIT, stream);
    launch_m(false, false, dim3(16, 16), HB_hi, HB_lo, nullptr, 0, HB_hi, HB_lo,
             MD_, MD_, MD_, 0, nullf, nullptr, nullptr, HA_hi, HA_lo, MD_,
             scal, 0.f, nullptr, ME_SYMSPLIT16, stream);
    // power: 3x H5 + 4x G (= exactly 100 G-applies), plain launches, stream-ordered.
    for (int it = 0; it < 7; ++it) {
        const _Float16* mh = (it < 3) ? HA_hi : Eh;
        const _Float16* ml = (it < 3) ? HA_lo : El;
        const float* xin = (it & 1) ? Xb : Xa;
        float* xout = (it & 1) ? Xa : Xb;
        papply_kernel<<<MD_ / 4, 256, 0, stream>>>(mh, ml, xin, xout, (it >= 3) ? 1 : 0);
    }
    pfinal_kernel<<<1, 256, 0, stream>>>(Xb, Kp, scal);
    // Gamma0 = soft(eta*B, lam); ZtA = split(Gamma0^T)  (overwrites HB — dead now)
    g0_kernel<<<dim3(NF_ / 32, MD_ / 32), 256, 0, stream>>>(Bm, scal, Gamma, ZA_hi, ZA_lo);

    // ---- phase 2: FISTA in Gram domain, A = E (2-product), Z ping-pong ----
    {
        float t = 1.f;
        for (int k = 0; k < FITER; ++k) {
            float tn = (1.0f + sqrtf(1.0f + (4.0f * t) * t)) / 2.0f;
            float beta = (t - 1.0f) / tn;
            t = tn;
            _Float16* in_hi  = (k & 1) ? ZB_hi : ZA_hi;
            _Float16* in_lo  = (k & 1) ? ZB_lo : ZA_lo;
            _Float16* out_hi = (k & 1) ? ZA_hi : ZB_hi;
            _Float16* out_lo = (k & 1) ? ZA_lo : ZB_lo;
            launch_m(false, false, dim3(32, 16), Eh, El, nullptr, 0, in_hi, in_lo,
                     MD_, MD_, NF_, NF_, Gamma, Bm, nullptr,
                     out_hi, out_lo, MD_, scal, beta, scal + 5 + k,
                     (k == FITER - 1) ? ME_FISTAG_LAST : ME_FISTAG, stream);
        }
        // FITER=20 even: final Gamma-split lands in ZA (ws); ZB (x_dec slab) is dead
    }

    // ---- phase 3: decode + GCN tail (all 2-product staged MFMA) ----
    splitadj_hi_kernel<<<2816, 256, 0, stream>>>(adj, adjT_hi);        // Bm dead now
    splitrows_hi_kernel<<<2816, 256, 0, stream>>>(Wd, NN_, MD_, Wh);
    // x_dec = W @ Gamma : A = Wh (2-product), B = ZA (Gamma^T split)
    launch_m(false, false, dim3(32, 22), Wh, Wh, nullptr, 0, ZA_hi, ZA_lo,
             MD_, NN_, NF_, NF_, x_dec, nullptr, nullptr,
             nullptr, nullptr, 0, scal, 0.f, nullptr, ME_STORE, stream);
    // xdh = hi(x_dec), overwrites dead ZA
    splitrows_hi_kernel<<<2816, 256, 0, stream>>>(x_dec, NN_, NF_, xdh);
    tsplit_kernel<<<dim3(NH_ / 32, NF_ / 32), 256, 0, stream>>>(gc1_w, NF_, NH_, NF_, g1t_hi, g1t_lo);
    fill0_kernel<<<(2785280 + 255) / 256, 256, 0, stream>>>((uint32_t*)xwT_hi, 2785280);
    // xw^T = split((x_dec @ gc1_w)^T) : A = xdh (2-product)
    launch_m(false, false, dim3(8, 22), xdh, xdh, nullptr, 0, g1t_hi, g1t_lo,
             NF_, NN_, NH_, 0, nullf, nullptr, nullptr,
             xwT_hi, xwT_lo, KPAD, scal, 0.f, nullptr, ME_SPLIT_T, stream);
    // h = relu(adj @ xw + b1) : A = adjT_hi (2-product); hbuf overwrites dead xdh
    launch_m(false, false, dim3(8, 22), adjT_hi, adjT_hi, nullptr, 0, xwT_hi, xwT_lo,
             KPAD, NN_, NH_, NH_, hbuf, nullptr, gc1_b,
             nullptr, nullptr, 0, scal, 0.f, nullptr, ME_BIASRELU, stream);
    fill0_kernel<<<(131072 + 255) / 256, 256, 0, stream>>>((uint32_t*)g2t_hi, 131072);
    tsplit_kernel<<<dim3(NC_ / 32, NH_ / 32), 256, 0, stream>>>(gc2_w, NH_, NC_, NH_, g2t_hi, g2t_lo);
    fill0_kernel<<<(348160 + 255) / 256, 256, 0, stream>>>((uint32_t*)hwT_hi, 348160);
    // hw^T = split((h @ gc2_w)^T) : tiny, keep AFP32 3-product
    launch_m(true, true, dim3(1, 22), nullh, nullh, hbuf, NN_, g2t_hi, g2t_lo,
             NH_, NN_, NC_, 0, nullf, nullptr, nullptr,
             hwT_hi, hwT_lo, KPAD, scal, 0.f, nullptr, ME_SPLIT_T, stream);
    // o = adj @ hw + b2 : A = adjT_hi (2-product)
    launch_m(false, false, dim3(1, 22), adjT_hi, adjT_hi, nullptr, 0, hwT_hi, hwT_lo,
             KPAD, NN_, NC_, NC_, obuf, nullptr, gc2_b,
             nullptr, nullptr, 0, scal, 0.f, nullptr, ME_BIAS, stream);
    logsoftmax_kernel<<<(NN_ + 3) / 4, 256, 0, stream>>>(obuf, logp);
    norms_kernel<<<1, 32, 0, stream>>>(scal, norms_o);
}